// Round 17
// baseline (240.955 us; speedup 1.0000x reference)
//
#include <hip/hip_runtime.h>
#include <hip/hip_bf16.h>

#define B_    8
#define N_    2048
#define FIN_  256
#define FOUT_ 128
#define NROWS (B_*N_)

typedef __attribute__((ext_vector_type(8))) short short8;
typedef __attribute__((ext_vector_type(4))) float f32x4;

__device__ __forceinline__ float bf2f(unsigned short u) {
  return __uint_as_float(((unsigned int)u) << 16);
}
__device__ __forceinline__ unsigned short f2bf(float f) {
  unsigned int u = __float_as_uint(f);
  u += 0x7FFFu + ((u >> 16) & 1u);   // RNE
  return (unsigned short)(u >> 16);
}
__device__ __forceinline__ float ldin(const void* p, size_t idx, int isbf) {
  if (isbf) return bf2f(((const unsigned short*)p)[idx]);
  return ((const float*)p)[idx];
}
__device__ __forceinline__ unsigned pk2bf(float a, float b) {
  return (unsigned)f2bf(a) | ((unsigned)f2bf(b) << 16);   // low = a (RNE)
}
// monotone float<->uint encoding for atomicMax float-max (all finite enc > 0)
__device__ __forceinline__ unsigned encf(float f) {
  unsigned u = __float_as_uint(f);
  return (u & 0x80000000u) ? ~u : (u | 0x80000000u);
}
__device__ __forceinline__ float decf(unsigned k) {
  return (k & 0x80000000u) ? __uint_as_float(k ^ 0x80000000u) : __uint_as_float(~k);
}
// per-block dtype self-detect (deterministic across blocks)
__device__ __forceinline__ int detect_bf(const void* x, int* cnt) {
  const unsigned short* u = (const unsigned short*)x;
  int c = 0;
  for (int i = threadIdx.x; i < 8192; i += 256) {
    unsigned short v = u[i];
    int e = (v >> 7) & 0xFF;
    if ((e >= 110 && e <= 145) || (v & 0x7FFF) == 0) c++;
  }
  cnt[threadIdx.x] = c;
  __syncthreads();
  for (int s = 128; s > 0; s >>= 1) {
    if (threadIdx.x < s) cnt[threadIdx.x] += cnt[threadIdx.x + s];
    __syncthreads();
  }
  return cnt[0] > 7373;   // 0.9 * 8192
}

// ---------- kernel 0: self-detect; blocks 0..127: WT; block 128: wa, flag,
//            MdstE init ----------
__global__ __launch_bounds__(256)
void k_prep(const void* __restrict__ x, const void* __restrict__ W,
            const void* __restrict__ a,
            unsigned short* __restrict__ WT, float* __restrict__ wa,
            int* __restrict__ flag, unsigned* __restrict__ MdstE) {
  __shared__ int cnt[256];
  const int isbf = detect_bf(x, cnt);
  if (blockIdx.x < 128) {
    int f = blockIdx.x, k = threadIdx.x;
    WT[f * 256 + k] = f2bf(ldin(W, (size_t)k * 128 + f, isbf));
  } else {
    __shared__ float as_s[256];
    int k = threadIdx.x;
    as_s[k] = ldin(a, k, isbf);
    __syncthreads();
    float s = 0.f, d = 0.f;
    for (int f = 0; f < 128; f++) {
      float w = ldin(W, (size_t)k * 128 + f, isbf);
      s += w * as_s[f];
      d += w * as_s[128 + f];
    }
    wa[k] = s;
    wa[256 + k] = d;
    if (k == 0) *flag = isbf;
    if (k < 8) MdstE[k * 32] = 0u;     // 0 < enc(f) for all finite f
  }
}

// ---------- kernel 1: h = x@W bf16 MFMA -> hT; fused fsrc/fdst = x@wa;
//            fused per-batch fdst max via 1 padded atomic per block ----------
__global__ __launch_bounds__(256)
void k_h(const void* __restrict__ x, const unsigned short* __restrict__ WT,
         const float* __restrict__ wa, const int* __restrict__ flag,
         unsigned short* __restrict__ hT, float* __restrict__ fsrc,
         float* __restrict__ fdst, unsigned* __restrict__ MdstE) {
  __shared__ __align__(16) unsigned short xs[32][264];
  __shared__ float wa_s[512];
  __shared__ float mxs[8];
  const int isbf = *flag;
  const int t    = threadIdx.x;
  const int row0 = blockIdx.x * 32;

  wa_s[t] = wa[t];
  wa_s[256 + t] = wa[256 + t];
  __syncthreads();

  const int c = t & 31;
  float sp[4], dp[4];
  if (isbf) {
    const unsigned short* xu = (const unsigned short*)x;
#pragma unroll
    for (int u = 0; u < 4; u++) {
      int r = u * 8 + (t >> 5);
      short8 sh = *(const short8*)&xu[(size_t)(row0 + r) * FIN_ + c * 8];
      *(short8*)&xs[r][c * 8] = sh;
      float s = 0.f, d = 0.f;
#pragma unroll
      for (int e = 0; e < 8; e++) {
        float xv = bf2f((unsigned short)sh[e]);
        s += xv * wa_s[c * 8 + e];
        d += xv * wa_s[256 + c * 8 + e];
      }
      sp[u] = s; dp[u] = d;
    }
  } else {
    const float* xf = (const float*)x;
#pragma unroll
    for (int u = 0; u < 4; u++) {
      int r = u * 8 + (t >> 5);
      float4 v0 = *(const float4*)&xf[(size_t)(row0 + r) * FIN_ + c * 8];
      float4 v1 = *(const float4*)&xf[(size_t)(row0 + r) * FIN_ + c * 8 + 4];
      float vv[8] = {v0.x, v0.y, v0.z, v0.w, v1.x, v1.y, v1.z, v1.w};
      short8 sh;
      float s = 0.f, d = 0.f;
#pragma unroll
      for (int e = 0; e < 8; e++) {
        sh[e] = (short)f2bf(vv[e]);
        s += vv[e] * wa_s[c * 8 + e];
        d += vv[e] * wa_s[256 + c * 8 + e];
      }
      *(short8*)&xs[r][c * 8] = sh;
      sp[u] = s; dp[u] = d;
    }
  }
#pragma unroll
  for (int off = 16; off >= 1; off >>= 1) {
#pragma unroll
    for (int u = 0; u < 4; u++) {
      sp[u] += __shfl_xor(sp[u], off, 64);
      dp[u] += __shfl_xor(dp[u], off, 64);
    }
  }
  if (c == 0) {
    float lm = -1e30f;
#pragma unroll
    for (int u = 0; u < 4; u++) {
      int r = u * 8 + (t >> 5);
      fsrc[row0 + r] = sp[u];
      fdst[row0 + r] = dp[u];
      lm = fmaxf(lm, dp[u]);
    }
    mxs[t >> 5] = lm;
  }
  __syncthreads();
  if (t == 0) {
    float m8 = mxs[0];
#pragma unroll
    for (int i = 1; i < 8; i++) m8 = fmaxf(m8, mxs[i]);
    atomicMax(&MdstE[(row0 >> 11) * 32], encf(m8));   // 64 atomics/line, padded
  }

  const int lane = t & 63, w = t >> 6;
  const int m = lane & 15, quad = lane >> 4;
  const int slab = w >> 1, fh = w & 1;

  f32x4 acc[4];
#pragma unroll
  for (int i = 0; i < 4; i++) acc[i] = (f32x4){0.f, 0.f, 0.f, 0.f};

#pragma unroll
  for (int ks = 0; ks < 8; ks++) {
    short8 ah = *(const short8*)&xs[slab * 16 + m][ks * 32 + quad * 8];
#pragma unroll
    for (int ft = 0; ft < 4; ft++) {
      int f = fh * 64 + ft * 16 + m;
      short8 bh = *(const short8*)&WT[(size_t)f * 256 + ks * 32 + quad * 8];
      acc[ft] = __builtin_amdgcn_mfma_f32_16x16x32_bf16(ah, bh, acc[ft], 0, 0, 0);
    }
  }

  size_t n0 = (size_t)blockIdx.x * 2 + slab;
  unsigned short* hblk = hT + n0 * (FOUT_ * 16);
#pragma unroll
  for (int ft = 0; ft < 4; ft++) {
    int f = fh * 64 + ft * 16 + m;
    *(uint2*)&hblk[f * 16 + quad * 4] = make_uint2(
        pk2bf(acc[ft][0], acc[ft][1]), pk2bf(acc[ft][2], acc[ft][3]));
  }
}

// ---------- kernel 2: single-pass gated attention, 16-q blocks, 128-j tiles -
// Grid = B*(N/16) = 1024 blocks. The two independently-verified best pieces
// combined on the verified shape:
//  * r10's dual-set register prefetch: bnxt loaded at top of iter t (before
//    logits+barrier), copied to bcur after MFMA. Written-before-barrier /
//    read-after keeps the loads early (r10 VGPR=64 proves compiler kept it).
//  * r14's logit path: native __expf, d2-gate, ones-column MFMA denominator.
//  * epilogue elu via __expf(v)-1 (not libm expm1f).
__global__ __launch_bounds__(256, 6)
void k_attn(const unsigned short* __restrict__ hT, const void* __restrict__ coord,
            const float* __restrict__ fsrc, const float* __restrict__ fdst,
            const unsigned* __restrict__ MdstE, const int* __restrict__ flag,
            void* __restrict__ out) {
  const int isbf = *flag;
  const int tid = threadIdx.x;
  const int b   = blockIdx.x >> 7;
  const int q0  = (blockIdx.x & 127) * 16;

  __shared__ __align__(16) float4 cjs[1024];            // 16 KB (cx,cy,cz,fdst)
  __shared__ __align__(16) unsigned short phi[2][16][136];

  const int qA   = tid & 15;
  const int jseg = tid >> 4;                            // 0..15, 8 j's each
  const size_t qglb = (size_t)b * N_ + q0 + qA;
  const float cq0 = ldin(coord, qglb * 3 + 0, isbf);
  const float cq1 = ldin(coord, qglb * 3 + 1, isbf);
  const float cq2 = ldin(coord, qglb * 3 + 2, isbf);
  const float fsq = fsrc[qglb];
  const float Bq  = fmaxf(0.f, fsq + decf(MdstE[b * 32]));

  const int lane = tid & 63, w = tid >> 6;
  const int m = lane & 15, quad = lane >> 4;
  f32x4 acc[2], accD;
  acc[0] = (f32x4){0.f, 0.f, 0.f, 0.f};
  acc[1] = (f32x4){0.f, 0.f, 0.f, 0.f};
  accD   = (f32x4){0.f, 0.f, 0.f, 0.f};
  const short8 bones = {(short)0x3F80, (short)0x3F80, (short)0x3F80, (short)0x3F80,
                        (short)0x3F80, (short)0x3F80, (short)0x3F80, (short)0x3F80};

  const unsigned short* hTb = hT + (size_t)b * (N_ * FOUT_);
  const int colA = (w * 2 + 0) * 16 + m;
  const int colB = (w * 2 + 1) * 16 + m;
  const int co   = (quad & 1) * 8;
  const int chq  = quad >> 1;

  // stage half 0 (j in [0,1024)) with all 256 threads
  for (int r = tid; r < 1024; r += 256) {
    size_t jg = (size_t)b * N_ + r;
    cjs[r] = make_float4(ldin(coord, jg * 3 + 0, isbf), ldin(coord, jg * 3 + 1, isbf),
                         ldin(coord, jg * 3 + 2, isbf), fdst[jg]);
  }
  // tile-0 B-fragments
  short8 bcur[8], bnxt[8];
#pragma unroll
  for (int ks = 0; ks < 4; ks++) {
    size_t base = (size_t)(ks * 2 + chq) * (FOUT_ * 16) + co;
    bcur[ks * 2 + 0] = *(const short8*)&hTb[base + colA * 16];
    bcur[ks * 2 + 1] = *(const short8*)&hTb[base + colB * 16];
  }
  __syncthreads();

  for (int t = 0; t < 16; t++) {
    if (t == 8) {
      // all waves past barrier_7 (done reading half 0); restage half 1
      for (int r = tid; r < 1024; r += 256) {
        size_t jg = (size_t)b * N_ + 1024 + r;
        cjs[r] = make_float4(ldin(coord, jg * 3 + 0, isbf), ldin(coord, jg * 3 + 1, isbf),
                             ldin(coord, jg * 3 + 2, isbf), fdst[jg]);
      }
      __syncthreads();
    }
    const int buf = t & 1;

    // prefetch NEXT tile's B-fragments (issued before logits+barrier,
    // consumed after the next barrier -- full-tile latency cover)
    if (t < 15) {
      const int jcb = (t + 1) * 8;
#pragma unroll
      for (int ks = 0; ks < 4; ks++) {
        size_t base = (size_t)(jcb + ks * 2 + chq) * (FOUT_ * 16) + co;
        bnxt[ks * 2 + 0] = *(const short8*)&hTb[base + colA * 16];
        bnxt[ks * 2 + 1] = *(const short8*)&hTb[base + colB * 16];
      }
    }

    // ---- logits: 8 j's -> packed bf16 -> one uint4 LDS store ----
    const int jbase = (t & 7) * 128 + jseg * 8;
    unsigned pk[4];
#pragma unroll
    for (int jp = 0; jp < 4; jp++) {
      float pv[2];
#pragma unroll
      for (int h = 0; h < 2; h++) {
        float4 cj = cjs[jbase + jp * 2 + h];
        float dx = cq0 - cj.x, dy = cq1 - cj.y, dz = cq2 - cj.z;
        float d2 = dx * dx + dy * dy + dz * dz;
        float loc = __expf(-0.1f * d2);
        float e = fsq + cj.w;
        e = fmaxf(e, 0.2f * e);                       // leaky relu
        float p = (d2 < 46.0517f) ? __expf(fmaf(e, loc, -Bq)) : 0.f;
        pv[h] = p;
      }
      pk[jp] = pk2bf(pv[0], pv[1]);
    }
    *(uint4*)&phi[buf][qA][jseg * 8] = make_uint4(pk[0], pk[1], pk[2], pk[3]);
    __syncthreads();   // one barrier per 128-j tile

    // ---- PV MFMA: 4 k-steps of 32, 2 f-tiles + ones-column denominator ----
#pragma unroll
    for (int ks = 0; ks < 4; ks++) {
      short8 ah = *(const short8*)&phi[buf][m][ks * 32 + quad * 8];
      acc[0] = __builtin_amdgcn_mfma_f32_16x16x32_bf16(ah, bcur[ks * 2 + 0], acc[0], 0, 0, 0);
      acc[1] = __builtin_amdgcn_mfma_f32_16x16x32_bf16(ah, bcur[ks * 2 + 1], acc[1], 0, 0, 0);
      accD   = __builtin_amdgcn_mfma_f32_16x16x32_bf16(ah, bones, accD, 0, 0, 0);
    }
#pragma unroll
    for (int i = 0; i < 8; i++) bcur[i] = bnxt[i];
  }

  // ---- normalize, elu, store (D: row q = quad*4+r, col f); accD[r] holds
  //      the full denominator for row q (every column equal) ----
#pragma unroll
  for (int f2 = 0; f2 < 2; f2++) {
    int f = (w * 2 + f2) * 16 + m;
#pragma unroll
    for (int r = 0; r < 4; r++) {
      int q = quad * 4 + r;
      float v = acc[f2][r] / fmaxf(accD[r], 1e-30f);
      v = (v > 0.f) ? v : (__expf(v) - 1.0f);
      size_t oidx = ((size_t)(b * N_ + q0 + q)) * FOUT_ + f;
      if (isbf) ((unsigned short*)out)[oidx] = f2bf(v);
      else      ((float*)out)[oidx] = v;
    }
  }
}

extern "C" void kernel_launch(void* const* d_in, const int* in_sizes, int n_in,
                              void* d_out, int out_size, void* d_ws, size_t ws_size,
                              hipStream_t stream) {
  const void* x     = d_in[0];
  const void* coord = d_in[1];
  const void* W     = d_in[2];
  const void* a     = d_in[3];

  // ws: [512-float header: flag@0, MdstE @ uint 64 (stride 32)]
  //     [hT][WT][wa][fsrc][fdst]
  int*            flag  = (int*)d_ws;
  unsigned*       MdstE = (unsigned*)d_ws + 64;
  unsigned short* hT    = (unsigned short*)((float*)d_ws + 512);
  unsigned short* WT    = hT + (size_t)NROWS * FOUT_;
  float*          wa    = (float*)(WT + 128 * 256);
  float*          fsrc  = wa + 512;
  float*          fdst  = fsrc + NROWS;

  k_prep<<<129, 256, 0, stream>>>(x, W, a, WT, wa, flag, MdstE);
  k_h   <<<NROWS / 32, 256, 0, stream>>>(x, WT, wa, flag, hT, fsrc, fdst, MdstE);
  k_attn<<<B_ * (N_ / 16), 256, 0, stream>>>(hT, coord, fsrc, fdst, MdstE, flag, d_out);
}

// Round 18
// 140.276 us; speedup vs baseline: 1.7177x; 1.7177x over previous
//
#include <hip/hip_runtime.h>
#include <hip/hip_bf16.h>

#define B_    8
#define N_    2048
#define FIN_  256
#define FOUT_ 128
#define NROWS (B_*N_)

typedef __attribute__((ext_vector_type(8))) short short8;
typedef __attribute__((ext_vector_type(4))) float f32x4;

__device__ __forceinline__ float bf2f(unsigned short u) {
  return __uint_as_float(((unsigned int)u) << 16);
}
__device__ __forceinline__ unsigned short f2bf(float f) {
  unsigned int u = __float_as_uint(f);
  u += 0x7FFFu + ((u >> 16) & 1u);   // RNE
  return (unsigned short)(u >> 16);
}
__device__ __forceinline__ float ldin(const void* p, size_t idx, int isbf) {
  if (isbf) return bf2f(((const unsigned short*)p)[idx]);
  return ((const float*)p)[idx];
}
__device__ __forceinline__ unsigned pk2bf(float a, float b) {
  return (unsigned)f2bf(a) | ((unsigned)f2bf(b) << 16);   // low = a (RNE)
}
// monotone float<->uint encoding for atomicMax float-max (all finite enc > 0)
__device__ __forceinline__ unsigned encf(float f) {
  unsigned u = __float_as_uint(f);
  return (u & 0x80000000u) ? ~u : (u | 0x80000000u);
}
__device__ __forceinline__ float decf(unsigned k) {
  return (k & 0x80000000u) ? __uint_as_float(k ^ 0x80000000u) : __uint_as_float(~k);
}
// per-block dtype self-detect (deterministic across blocks)
__device__ __forceinline__ int detect_bf(const void* x, int* cnt) {
  const unsigned short* u = (const unsigned short*)x;
  int c = 0;
  for (int i = threadIdx.x; i < 8192; i += 256) {
    unsigned short v = u[i];
    int e = (v >> 7) & 0xFF;
    if ((e >= 110 && e <= 145) || (v & 0x7FFF) == 0) c++;
  }
  cnt[threadIdx.x] = c;
  __syncthreads();
  for (int s = 128; s > 0; s >>= 1) {
    if (threadIdx.x < s) cnt[threadIdx.x] += cnt[threadIdx.x + s];
    __syncthreads();
  }
  return cnt[0] > 7373;   // 0.9 * 8192
}

// ---------- kernel 0: self-detect; blocks 0..127: WT; block 128: wa, flag,
//            MdstE init ----------
__global__ __launch_bounds__(256)
void k_prep(const void* __restrict__ x, const void* __restrict__ W,
            const void* __restrict__ a,
            unsigned short* __restrict__ WT, float* __restrict__ wa,
            int* __restrict__ flag, unsigned* __restrict__ MdstE) {
  __shared__ int cnt[256];
  const int isbf = detect_bf(x, cnt);
  if (blockIdx.x < 128) {
    int f = blockIdx.x, k = threadIdx.x;
    WT[f * 256 + k] = f2bf(ldin(W, (size_t)k * 128 + f, isbf));
  } else {
    __shared__ float as_s[256];
    int k = threadIdx.x;
    as_s[k] = ldin(a, k, isbf);
    __syncthreads();
    float s = 0.f, d = 0.f;
    for (int f = 0; f < 128; f++) {
      float w = ldin(W, (size_t)k * 128 + f, isbf);
      s += w * as_s[f];
      d += w * as_s[128 + f];
    }
    wa[k] = s;
    wa[256 + k] = d;
    if (k == 0) *flag = isbf;
    if (k < 8) MdstE[k * 32] = 0u;     // 0 < enc(f) for all finite f
  }
}

// ---------- kernel 1: h = x@W bf16 MFMA -> hT; fused fsrc/fdst = x@wa;
//            fused per-batch fdst max via 1 padded atomic per block ----------
__global__ __launch_bounds__(256)
void k_h(const void* __restrict__ x, const unsigned short* __restrict__ WT,
         const float* __restrict__ wa, const int* __restrict__ flag,
         unsigned short* __restrict__ hT, float* __restrict__ fsrc,
         float* __restrict__ fdst, unsigned* __restrict__ MdstE) {
  __shared__ __align__(16) unsigned short xs[32][264];
  __shared__ float wa_s[512];
  __shared__ float mxs[8];
  const int isbf = *flag;
  const int t    = threadIdx.x;
  const int row0 = blockIdx.x * 32;

  wa_s[t] = wa[t];
  wa_s[256 + t] = wa[256 + t];
  __syncthreads();

  const int c = t & 31;
  float sp[4], dp[4];
  if (isbf) {
    const unsigned short* xu = (const unsigned short*)x;
#pragma unroll
    for (int u = 0; u < 4; u++) {
      int r = u * 8 + (t >> 5);
      short8 sh = *(const short8*)&xu[(size_t)(row0 + r) * FIN_ + c * 8];
      *(short8*)&xs[r][c * 8] = sh;
      float s = 0.f, d = 0.f;
#pragma unroll
      for (int e = 0; e < 8; e++) {
        float xv = bf2f((unsigned short)sh[e]);
        s += xv * wa_s[c * 8 + e];
        d += xv * wa_s[256 + c * 8 + e];
      }
      sp[u] = s; dp[u] = d;
    }
  } else {
    const float* xf = (const float*)x;
#pragma unroll
    for (int u = 0; u < 4; u++) {
      int r = u * 8 + (t >> 5);
      float4 v0 = *(const float4*)&xf[(size_t)(row0 + r) * FIN_ + c * 8];
      float4 v1 = *(const float4*)&xf[(size_t)(row0 + r) * FIN_ + c * 8 + 4];
      float vv[8] = {v0.x, v0.y, v0.z, v0.w, v1.x, v1.y, v1.z, v1.w};
      short8 sh;
      float s = 0.f, d = 0.f;
#pragma unroll
      for (int e = 0; e < 8; e++) {
        sh[e] = (short)f2bf(vv[e]);
        s += vv[e] * wa_s[c * 8 + e];
        d += vv[e] * wa_s[256 + c * 8 + e];
      }
      *(short8*)&xs[r][c * 8] = sh;
      sp[u] = s; dp[u] = d;
    }
  }
#pragma unroll
  for (int off = 16; off >= 1; off >>= 1) {
#pragma unroll
    for (int u = 0; u < 4; u++) {
      sp[u] += __shfl_xor(sp[u], off, 64);
      dp[u] += __shfl_xor(dp[u], off, 64);
    }
  }
  if (c == 0) {
    float lm = -1e30f;
#pragma unroll
    for (int u = 0; u < 4; u++) {
      int r = u * 8 + (t >> 5);
      fsrc[row0 + r] = sp[u];
      fdst[row0 + r] = dp[u];
      lm = fmaxf(lm, dp[u]);
    }
    mxs[t >> 5] = lm;
  }
  __syncthreads();
  if (t == 0) {
    float m8 = mxs[0];
#pragma unroll
    for (int i = 1; i < 8; i++) m8 = fmaxf(m8, mxs[i]);
    atomicMax(&MdstE[(row0 >> 11) * 32], encf(m8));   // 64 atomics/line, padded
  }

  const int lane = t & 63, w = t >> 6;
  const int m = lane & 15, quad = lane >> 4;
  const int slab = w >> 1, fh = w & 1;

  f32x4 acc[4];
#pragma unroll
  for (int i = 0; i < 4; i++) acc[i] = (f32x4){0.f, 0.f, 0.f, 0.f};

#pragma unroll
  for (int ks = 0; ks < 8; ks++) {
    short8 ah = *(const short8*)&xs[slab * 16 + m][ks * 32 + quad * 8];
#pragma unroll
    for (int ft = 0; ft < 4; ft++) {
      int f = fh * 64 + ft * 16 + m;
      short8 bh = *(const short8*)&WT[(size_t)f * 256 + ks * 32 + quad * 8];
      acc[ft] = __builtin_amdgcn_mfma_f32_16x16x32_bf16(ah, bh, acc[ft], 0, 0, 0);
    }
  }

  size_t n0 = (size_t)blockIdx.x * 2 + slab;
  unsigned short* hblk = hT + n0 * (FOUT_ * 16);
#pragma unroll
  for (int ft = 0; ft < 4; ft++) {
    int f = fh * 64 + ft * 16 + m;
    *(uint2*)&hblk[f * 16 + quad * 4] = make_uint2(
        pk2bf(acc[ft][0], acc[ft][1]), pk2bf(acc[ft][2], acc[ft][3]));
  }
}

// ---------- kernel 2: single-pass gated attention, 16-q blocks, 128-j tiles -
// Grid = B*(N/16) = 1024 blocks (= 4 blocks/CU, the residency limit).
// __launch_bounds__(256, 4): the dual-set B-prefetch needs the ~128-VGPR
// budget -- at (256,6) the allocator spills bcur/bnxt to scratch (r17:
// WRITE_SIZE 394 MB, 3x slowdown). r10 proved (256,4) keeps it in registers.
// Logit path: native __expf, d2-gate, ones-column MFMA denominator (r14).
__global__ __launch_bounds__(256, 4)
void k_attn(const unsigned short* __restrict__ hT, const void* __restrict__ coord,
            const float* __restrict__ fsrc, const float* __restrict__ fdst,
            const unsigned* __restrict__ MdstE, const int* __restrict__ flag,
            void* __restrict__ out) {
  const int isbf = *flag;
  const int tid = threadIdx.x;
  const int b   = blockIdx.x >> 7;
  const int q0  = (blockIdx.x & 127) * 16;

  __shared__ __align__(16) float4 cjs[1024];            // 16 KB (cx,cy,cz,fdst)
  __shared__ __align__(16) unsigned short phi[2][16][136];

  const int qA   = tid & 15;
  const int jseg = tid >> 4;                            // 0..15, 8 j's each
  const size_t qglb = (size_t)b * N_ + q0 + qA;
  const float cq0 = ldin(coord, qglb * 3 + 0, isbf);
  const float cq1 = ldin(coord, qglb * 3 + 1, isbf);
  const float cq2 = ldin(coord, qglb * 3 + 2, isbf);
  const float fsq = fsrc[qglb];
  const float Bq  = fmaxf(0.f, fsq + decf(MdstE[b * 32]));

  const int lane = tid & 63, w = tid >> 6;
  const int m = lane & 15, quad = lane >> 4;
  f32x4 acc[2], accD;
  acc[0] = (f32x4){0.f, 0.f, 0.f, 0.f};
  acc[1] = (f32x4){0.f, 0.f, 0.f, 0.f};
  accD   = (f32x4){0.f, 0.f, 0.f, 0.f};
  const short8 bones = {(short)0x3F80, (short)0x3F80, (short)0x3F80, (short)0x3F80,
                        (short)0x3F80, (short)0x3F80, (short)0x3F80, (short)0x3F80};

  const unsigned short* hTb = hT + (size_t)b * (N_ * FOUT_);
  const int colA = (w * 2 + 0) * 16 + m;
  const int colB = (w * 2 + 1) * 16 + m;
  const int co   = (quad & 1) * 8;
  const int chq  = quad >> 1;

  // stage half 0 (j in [0,1024)) with all 256 threads
  for (int r = tid; r < 1024; r += 256) {
    size_t jg = (size_t)b * N_ + r;
    cjs[r] = make_float4(ldin(coord, jg * 3 + 0, isbf), ldin(coord, jg * 3 + 1, isbf),
                         ldin(coord, jg * 3 + 2, isbf), fdst[jg]);
  }
  // tile-0 B-fragments
  short8 bcur[8], bnxt[8];
#pragma unroll
  for (int ks = 0; ks < 4; ks++) {
    size_t base = (size_t)(ks * 2 + chq) * (FOUT_ * 16) + co;
    bcur[ks * 2 + 0] = *(const short8*)&hTb[base + colA * 16];
    bcur[ks * 2 + 1] = *(const short8*)&hTb[base + colB * 16];
  }
  __syncthreads();

  for (int t = 0; t < 16; t++) {
    if (t == 8) {
      // all waves past barrier_7 (done reading half 0); restage half 1
      for (int r = tid; r < 1024; r += 256) {
        size_t jg = (size_t)b * N_ + 1024 + r;
        cjs[r] = make_float4(ldin(coord, jg * 3 + 0, isbf), ldin(coord, jg * 3 + 1, isbf),
                             ldin(coord, jg * 3 + 2, isbf), fdst[jg]);
      }
      __syncthreads();
    }
    const int buf = t & 1;

    // prefetch NEXT tile's B-fragments (issued before logits+barrier,
    // consumed after the next barrier -- full-tile latency cover)
    if (t < 15) {
      const int jcb = (t + 1) * 8;
#pragma unroll
      for (int ks = 0; ks < 4; ks++) {
        size_t base = (size_t)(jcb + ks * 2 + chq) * (FOUT_ * 16) + co;
        bnxt[ks * 2 + 0] = *(const short8*)&hTb[base + colA * 16];
        bnxt[ks * 2 + 1] = *(const short8*)&hTb[base + colB * 16];
      }
    }

    // ---- logits: 8 j's -> packed bf16 -> one uint4 LDS store ----
    const int jbase = (t & 7) * 128 + jseg * 8;
    unsigned pk[4];
#pragma unroll
    for (int jp = 0; jp < 4; jp++) {
      float pv[2];
#pragma unroll
      for (int h = 0; h < 2; h++) {
        float4 cj = cjs[jbase + jp * 2 + h];
        float dx = cq0 - cj.x, dy = cq1 - cj.y, dz = cq2 - cj.z;
        float d2 = dx * dx + dy * dy + dz * dz;
        float loc = __expf(-0.1f * d2);
        float e = fsq + cj.w;
        e = fmaxf(e, 0.2f * e);                       // leaky relu
        float p = (d2 < 46.0517f) ? __expf(fmaf(e, loc, -Bq)) : 0.f;
        pv[h] = p;
      }
      pk[jp] = pk2bf(pv[0], pv[1]);
    }
    *(uint4*)&phi[buf][qA][jseg * 8] = make_uint4(pk[0], pk[1], pk[2], pk[3]);
    __syncthreads();   // one barrier per 128-j tile

    // ---- PV MFMA: 4 k-steps of 32, 2 f-tiles + ones-column denominator ----
#pragma unroll
    for (int ks = 0; ks < 4; ks++) {
      short8 ah = *(const short8*)&phi[buf][m][ks * 32 + quad * 8];
      acc[0] = __builtin_amdgcn_mfma_f32_16x16x32_bf16(ah, bcur[ks * 2 + 0], acc[0], 0, 0, 0);
      acc[1] = __builtin_amdgcn_mfma_f32_16x16x32_bf16(ah, bcur[ks * 2 + 1], acc[1], 0, 0, 0);
      accD   = __builtin_amdgcn_mfma_f32_16x16x32_bf16(ah, bones, accD, 0, 0, 0);
    }
#pragma unroll
    for (int i = 0; i < 8; i++) bcur[i] = bnxt[i];
  }

  // ---- normalize, elu, store (D: row q = quad*4+r, col f); accD[r] holds
  //      the full denominator for row q (every column equal) ----
#pragma unroll
  for (int f2 = 0; f2 < 2; f2++) {
    int f = (w * 2 + f2) * 16 + m;
#pragma unroll
    for (int r = 0; r < 4; r++) {
      int q = quad * 4 + r;
      float v = acc[f2][r] / fmaxf(accD[r], 1e-30f);
      v = (v > 0.f) ? v : (__expf(v) - 1.0f);
      size_t oidx = ((size_t)(b * N_ + q0 + q)) * FOUT_ + f;
      if (isbf) ((unsigned short*)out)[oidx] = f2bf(v);
      else      ((float*)out)[oidx] = v;
    }
  }
}

extern "C" void kernel_launch(void* const* d_in, const int* in_sizes, int n_in,
                              void* d_out, int out_size, void* d_ws, size_t ws_size,
                              hipStream_t stream) {
  const void* x     = d_in[0];
  const void* coord = d_in[1];
  const void* W     = d_in[2];
  const void* a     = d_in[3];

  // ws: [512-float header: flag@0, MdstE @ uint 64 (stride 32)]
  //     [hT][WT][wa][fsrc][fdst]
  int*            flag  = (int*)d_ws;
  unsigned*       MdstE = (unsigned*)d_ws + 64;
  unsigned short* hT    = (unsigned short*)((float*)d_ws + 512);
  unsigned short* WT    = hT + (size_t)NROWS * FOUT_;
  float*          wa    = (float*)(WT + 128 * 256);
  float*          fsrc  = wa + 512;
  float*          fdst  = fsrc + NROWS;

  k_prep<<<129, 256, 0, stream>>>(x, W, a, WT, wa, flag, MdstE);
  k_h   <<<NROWS / 32, 256, 0, stream>>>(x, WT, wa, flag, hT, fsrc, fdst, MdstE);
  k_attn<<<B_ * (N_ / 16), 256, 0, stream>>>(hT, coord, fsrc, fdst, MdstE, flag, d_out);
}